// Round 16
// baseline (665.645 us; speedup 1.0000x reference)
//
#include <hip/hip_runtime.h>

#define BN_EPS 1e-4f
#define NREP 16  // stats replica banks (atomic-contention spreading)

typedef _Float16 f16x8 __attribute__((ext_vector_type(8)));
typedef __fp16 h2 __attribute__((ext_vector_type(2)));
typedef float f32x4 __attribute__((ext_vector_type(4)));

// ---------------------------------------------------------------------------
// Build group-compacted rulebook, fixed-stride slots, byte-offset packing:
//   ent[(grp*27+e)*16 + l] = (idx << 5) | tap ; gcnt[grp] = active tap count.
__global__ __launch_bounds__(256) void build_k(
    const int* __restrict__ nbr, int N, int Nin, int ngroups,
    int* __restrict__ gcnt, int* __restrict__ ent)
{
    const int wave = threadIdx.x >> 6, lane = threadIdx.x & 63;
    const int l15 = lane & 15, q = lane >> 4;

    for (int grp = blockIdx.x * 4 + wave; grp < ngroups; grp += gridDim.x * 4) {
        const int site = grp * 16 + l15;
        int v[7];
        unsigned act = 0;
#pragma unroll
        for (int p = 0; p < 7; ++p) {
            const int t = 4 * p + q;
            int idx = Nin;
            if (t < 27 && site < N) idx = nbr[(size_t)t * N + site];
            v[p] = idx;
            const unsigned long long bal = __ballot(idx < Nin);
#pragma unroll
            for (int qq = 0; qq < 4; ++qq) {
                const int tt = 4 * p + qq;
                if (tt < 27 && ((bal >> (16 * qq)) & 0xFFFFull)) act |= 1u << tt;
            }
        }
        const int cnt = __popc(act);
        if (lane == 0) gcnt[grp] = cnt;
        const int e0 = grp * 27;
#pragma unroll
        for (int p = 0; p < 7; ++p) {
            const int t = 4 * p + q;
            if (t < 27 && ((act >> t) & 1)) {
                const int e = __popc(act & ((1u << t) - 1));   // rank
                ent[(size_t)(e0 + e) * 16 + l15] = (v[p] << 5) | t;
            }
        }
    }
}

// ---------------------------------------------------------------------------
// MFMA conv over the compacted rulebook, CIN=16, fused input BN+ReLU.
// R15/16: (a) BN+ReLU in PACKED fp16 (__fp16 vectors for cvt_pkrtz's return
// type; v_pk_fma/v_pk_max) — ~12 VALU/gather vs 20 fp32; (b) explicit 6-deep
// gather stage (24 VGPRs — safe vs R13's 56-VGPR spill); (c) grid cap 4096.
__global__ __launch_bounds__(256, 4) void conv16c_k(
    const float* __restrict__ act,      // [Nin, 16] fp32 PRE-BN
    const int* __restrict__ gcnt,       // [ngroups]
    const int* __restrict__ ent,        // [ngroups*27][16] packed
    const _Float16* __restrict__ WT,    // [27][2][16][8] per-tap B table
    const float* __restrict__ g,        // [16] BN gamma (input BN)
    const float* __restrict__ b,        // [16] BN beta
    const float* __restrict__ stats_in, // [NREP][128] stats of act
    float invN,
    float* __restrict__ out,            // [Nout, 16] fp32
    float* __restrict__ stats_out,      // [NREP][128] or nullptr
    int Nout, int Nin, int addSkip)
{
    __shared__ _Float16 WTs[27 * 2 * 16 * 8];  // 13824 B
    __shared__ float TRS[4][16 * 20];          // 5120 B
    __shared__ float RED[4][32];               // 512 B
    __shared__ float sbl[2][16];               // 128 B

    const int wave = threadIdx.x >> 6, lane = threadIdx.x & 63;
    const int l15 = lane & 15, q = lane >> 4;
    const int h = q & 1, th = q >> 1;
    const int SENT = Nin << 5;
    float* Tr = TRS[wave];

    {   // stage per-tap B table to LDS + compute BN scale/bias (once/block)
        const float4* s = (const float4*)WT;
        float4* d = (float4*)WTs;
        for (int v = threadIdx.x; v < 27 * 2 * 16; v += 256) d[v] = s[v];
        if (threadIdx.x < 16) {
            const int c = threadIdx.x;
            float su = 0.f, sq = 0.f;
#pragma unroll
            for (int rep = 0; rep < NREP; ++rep) {
                su += stats_in[rep * 128 + c];
                sq += stats_in[rep * 128 + 64 + c];
            }
            const float mean = su * invN;
            const float var = sq * invN - mean * mean;
            const float sc = g[c] * rsqrtf(var + BN_EPS);
            sbl[0][c] = sc;
            sbl[1][c] = fmaf(-mean, sc, b[c]);
        }
    }
    __syncthreads();

    // per-lane packed-fp16 BN constants for this lane's 8 input channels
    h2 sc2[4], bi2[4];
#pragma unroll
    for (int j = 0; j < 4; ++j) {
        sc2[j][0] = (__fp16)sbl[0][h * 8 + 2 * j];
        sc2[j][1] = (__fp16)sbl[0][h * 8 + 2 * j + 1];
        bi2[j][0] = (__fp16)sbl[1][h * 8 + 2 * j];
        bi2[j][1] = (__fp16)sbl[1][h * 8 + 2 * j + 1];
    }

    // gather + packed-fp16 BN+ReLU (exec-masked; a=0 for dead slots)
    auto gtr = [&](int raw) -> f16x8 {
        f16x8 a = {};
        if (raw < SENT) {
            const float* rp = act + ((size_t)(raw >> 5) * 16 + h * 8);
            const float4 x0 = ((const float4*)rp)[0];
            const float4 x1 = ((const float4*)rp)[1];
            const h2 z = {};
            h2 r0 = __builtin_amdgcn_cvt_pkrtz(x0.x, x0.y);
            h2 r1 = __builtin_amdgcn_cvt_pkrtz(x0.z, x0.w);
            h2 r2 = __builtin_amdgcn_cvt_pkrtz(x1.x, x1.y);
            h2 r3 = __builtin_amdgcn_cvt_pkrtz(x1.z, x1.w);
            r0 = __builtin_elementwise_max(r0 * sc2[0] + bi2[0], z);
            r1 = __builtin_elementwise_max(r1 * sc2[1] + bi2[1], z);
            r2 = __builtin_elementwise_max(r2 * sc2[2] + bi2[2], z);
            r3 = __builtin_elementwise_max(r3 * sc2[3] + bi2[3], z);
            a[0] = (_Float16)r0[0]; a[1] = (_Float16)r0[1];
            a[2] = (_Float16)r1[0]; a[3] = (_Float16)r1[1];
            a[4] = (_Float16)r2[0]; a[5] = (_Float16)r2[1];
            a[6] = (_Float16)r3[0]; a[7] = (_Float16)r3[1];
        }
        return a;
    };

    const int ngroups = (Nout + 15) >> 4;
    const int stride = gridDim.x * 4;
    const int rr = lane >> 2, cc = (lane & 3) * 4;
    float sj[4] = {0.f, 0.f, 0.f, 0.f}, qj[4] = {0.f, 0.f, 0.f, 0.f};

    int grp = blockIdx.x * 4 + wave;
    int cc_cur = 0, cc_nxt = 0;
    int pe[14];
    if (grp < ngroups) {
        cc_cur = gcnt[grp];
        const int g1 = grp + stride;
        if (g1 < ngroups) cc_nxt = gcnt[g1];
        const size_t e0 = (size_t)grp * 27;
#pragma unroll
        for (int pp = 0; pp < 14; ++pp) {
            const int sidx = 2 * pp + th;
            int r = SENT;
            if (sidx < cc_cur) r = ent[(e0 + sidx) * 16 + l15];
            pe[pp] = r;
        }
    }

    while (grp < ngroups) {
        int ce[14];
#pragma unroll
        for (int pp = 0; pp < 14; ++pp) ce[pp] = pe[pp];

        const int base = grp * 16, srow = base + rr;
        float4 skip = make_float4(0.f, 0.f, 0.f, 0.f);
        if (addSkip && srow < Nout)
            skip = *(const float4*)(out + (size_t)srow * 16 + cc);

        const int gn = grp + stride;
        int cc_nn = 0;
        if (gn < ngroups) {
            const size_t e0n = (size_t)gn * 27;
#pragma unroll
            for (int pp = 0; pp < 14; ++pp) {
                const int sidx = 2 * pp + th;
                int r = SENT;
                if (sidx < cc_nxt) r = ent[(e0n + sidx) * 16 + l15];
                pe[pp] = r;
            }
            const int gnn = gn + stride;
            if (gnn < ngroups) cc_nn = gcnt[gnn];
        }

        // ---- 6-deep software gather pipeline feeding the MFMA chain
        f16x8 st[6];
#pragma unroll
        for (int pp = 0; pp < 6; ++pp) st[pp] = gtr(ce[pp]);

        f32x4 acc0 = {0.f, 0.f, 0.f, 0.f}, acc1 = {0.f, 0.f, 0.f, 0.f};
#pragma unroll
        for (int pp = 0; pp < 14; ++pp) {
            const f16x8 a = st[pp % 6];
            if (pp + 6 < 14) st[pp % 6] = gtr(ce[pp + 6]);
            const int tap = ce[pp] & 31;
            const f16x8 bb = *(const f16x8*)(WTs + ((tap * 2 + h) * 16 + l15) * 8);
            if (pp & 1) acc1 = __builtin_amdgcn_mfma_f32_16x16x32_f16(a, bb, acc1, 0, 0, 0);
            else        acc0 = __builtin_amdgcn_mfma_f32_16x16x32_f16(a, bb, acc0, 0, 0, 0);
        }

#pragma unroll
        for (int r = 0; r < 4; ++r)
            Tr[(q * 4 + r) * 20 + l15] = acc0[r] + acc1[r];
        float4 v4;
        v4.x = Tr[rr * 20 + cc + 0] + skip.x;
        v4.y = Tr[rr * 20 + cc + 1] + skip.y;
        v4.z = Tr[rr * 20 + cc + 2] + skip.z;
        v4.w = Tr[rr * 20 + cc + 3] + skip.w;
        if (srow < Nout) {
            *(float4*)(out + (size_t)srow * 16 + cc) = v4;
            sj[0] += v4.x; qj[0] += v4.x * v4.x;
            sj[1] += v4.y; qj[1] += v4.y * v4.y;
            sj[2] += v4.z; qj[2] += v4.z * v4.z;
            sj[3] += v4.w; qj[3] += v4.w * v4.w;
        }
        cc_cur = cc_nxt; cc_nxt = cc_nn;
        grp = gn;
    }

    if (stats_out) {  // uniform branch (kernel arg)
#pragma unroll
        for (int m = 4; m < 64; m <<= 1) {
#pragma unroll
            for (int j = 0; j < 4; ++j) {
                sj[j] += __shfl_xor(sj[j], m);
                qj[j] += __shfl_xor(qj[j], m);
            }
        }
        if (lane < 4) {
#pragma unroll
            for (int j = 0; j < 4; ++j) {
                RED[wave][lane * 4 + j] = sj[j];
                RED[wave][16 + lane * 4 + j] = qj[j];
            }
        }
        __syncthreads();
        if (threadIdx.x < 32) {
            const int t2 = threadIdx.x;
            float* bank = stats_out + (blockIdx.x & (NREP - 1)) * 128;
            atomicAdd(bank + (t2 < 16 ? t2 : 48 + t2),
                      RED[0][t2] + RED[1][t2] + RED[2][t2] + RED[3][t2]);
        }
    }
}

// ---------------------------------------------------------------------------
// Dense-rulebook conv (K=8 down-convs), fused packed-fp16 input BN+ReLU.
template <int K>
__global__ __launch_bounds__(256, 4) void conv16_k(
    const float* __restrict__ act, const int* __restrict__ nbr,
    const _Float16* __restrict__ WB,
    const float* __restrict__ g, const float* __restrict__ b,
    const float* __restrict__ stats_in, float invN,
    float* __restrict__ out, float* __restrict__ stats_out,
    int Nout, int Nin, int addSkip)
{
    constexpr int PAIRS = (K + 1) / 2;
    __shared__ float sbl[2][16];
    const int wave = threadIdx.x >> 6, lane = threadIdx.x & 63;
    const int l15 = lane & 15, q = lane >> 4;
    const int h = q & 1, th = q >> 1;

    if (threadIdx.x < 16) {
        const int c = threadIdx.x;
        float su = 0.f, sq = 0.f;
#pragma unroll
        for (int rep = 0; rep < NREP; ++rep) {
            su += stats_in[rep * 128 + c];
            sq += stats_in[rep * 128 + 64 + c];
        }
        const float mean = su * invN;
        const float var = sq * invN - mean * mean;
        const float sc = g[c] * rsqrtf(var + BN_EPS);
        sbl[0][c] = sc;
        sbl[1][c] = fmaf(-mean, sc, b[c]);
    }
    __syncthreads();

    h2 sc2[4], bi2[4];
#pragma unroll
    for (int j = 0; j < 4; ++j) {
        sc2[j][0] = (__fp16)sbl[0][h * 8 + 2 * j];
        sc2[j][1] = (__fp16)sbl[0][h * 8 + 2 * j + 1];
        bi2[j][0] = (__fp16)sbl[1][h * 8 + 2 * j];
        bi2[j][1] = (__fp16)sbl[1][h * 8 + 2 * j + 1];
    }

    auto gtr = [&](int idx) -> f16x8 {
        f16x8 a = {};
        if (idx < Nin) {
            const float* rp = act + ((size_t)idx * 16 + h * 8);
            const float4 x0 = ((const float4*)rp)[0];
            const float4 x1 = ((const float4*)rp)[1];
            const h2 z = {};
            h2 r0 = __builtin_amdgcn_cvt_pkrtz(x0.x, x0.y);
            h2 r1 = __builtin_amdgcn_cvt_pkrtz(x0.z, x0.w);
            h2 r2 = __builtin_amdgcn_cvt_pkrtz(x1.x, x1.y);
            h2 r3 = __builtin_amdgcn_cvt_pkrtz(x1.z, x1.w);
            r0 = __builtin_elementwise_max(r0 * sc2[0] + bi2[0], z);
            r1 = __builtin_elementwise_max(r1 * sc2[1] + bi2[1], z);
            r2 = __builtin_elementwise_max(r2 * sc2[2] + bi2[2], z);
            r3 = __builtin_elementwise_max(r3 * sc2[3] + bi2[3], z);
            a[0] = (_Float16)r0[0]; a[1] = (_Float16)r0[1];
            a[2] = (_Float16)r1[0]; a[3] = (_Float16)r1[1];
            a[4] = (_Float16)r2[0]; a[5] = (_Float16)r2[1];
            a[6] = (_Float16)r3[0]; a[7] = (_Float16)r3[1];
        }
        return a;
    };

    f16x8 bfr[PAIRS];
#pragma unroll
    for (int p = 0; p < PAIRS; ++p)
        bfr[p] = *(const f16x8*)(WB + ((size_t)p * 64 + lane) * 8);

    const int ngroups = (Nout + 15) >> 4;
    float s = 0.f, ss = 0.f;

    for (int grp = blockIdx.x * 4 + wave; grp < ngroups; grp += gridDim.x * 4) {
        const int base = grp * 16;
        const int site = min(base + l15, Nout - 1);
        int idxs[PAIRS];
#pragma unroll
        for (int p = 0; p < PAIRS; ++p) {
            const int t = 2 * p + ((2 * p + 1 < K) ? th : 0);
            idxs[p] = nbr[(size_t)t * Nout + site];
        }
        f32x4 acc0 = {0.f, 0.f, 0.f, 0.f}, acc1 = {0.f, 0.f, 0.f, 0.f};
#pragma unroll
        for (int p = 0; p < PAIRS; ++p) {
            const f16x8 a = gtr(idxs[p]);
            if (p & 1) acc1 = __builtin_amdgcn_mfma_f32_16x16x32_f16(a, bfr[p], acc1, 0, 0, 0);
            else       acc0 = __builtin_amdgcn_mfma_f32_16x16x32_f16(a, bfr[p], acc0, 0, 0, 0);
        }
#pragma unroll
        for (int r = 0; r < 4; ++r) {
            const int row = base + q * 4 + r;
            float v = acc0[r] + acc1[r];
            if (row < Nout) {
                float* op = out + (size_t)row * 16 + l15;
                if (addSkip) v += *op;
                *op = v;
                s += v; ss += v * v;
            }
        }
    }

    if (stats_out) {
        s  += __shfl_xor(s, 16);  s  += __shfl_xor(s, 32);
        ss += __shfl_xor(ss, 16); ss += __shfl_xor(ss, 32);
        __shared__ float red[4][32];
        if (lane < 16) { red[wave][l15] = s; red[wave][16 + l15] = ss; }
        __syncthreads();
        if (threadIdx.x < 32) {
            const int t2 = threadIdx.x;
            float* bank = stats_out + (blockIdx.x & (NREP - 1)) * 128;
            atomicAdd(bank + (t2 < 16 ? t2 : 48 + t2),
                      red[0][t2] + red[1][t2] + red[2][t2] + red[3][t2]);
        }
    }
}

// ---------------------------------------------------------------------------
// p1 conv (CIN=2): gathers raw fp32 feats (cvt in register), masked.
__global__ __launch_bounds__(256, 4) void convp1_k(
    const float* __restrict__ feats,    // [N0, 2] fp32
    const int* __restrict__ nbr,        // [27, N0]
    const _Float16* __restrict__ WB,    // [2][64][8]
    float* __restrict__ out, float* __restrict__ stats_out, int N)
{
    const int wave = threadIdx.x >> 6, lane = threadIdx.x & 63;
    const int l15 = lane & 15, q = lane >> 4;

    f16x8 b0 = *(const f16x8*)(WB + (size_t)lane * 8);
    f16x8 b1 = *(const f16x8*)(WB + ((size_t)64 + lane) * 8);

    const int ngroups = (N + 15) >> 4;
    float s = 0.f, ss = 0.f;

    for (int grp = blockIdx.x * 4 + wave; grp < ngroups; grp += gridDim.x * 4) {
        const int base = grp * 16;
        const int site = min(base + l15, N - 1);
        int tid[8];
#pragma unroll
        for (int u = 0; u < 8; ++u) {
            const int t = (u < 4) ? (q * 4 + u) : (16 + q * 4 + (u - 4));
            tid[u] = (t < 27) ? nbr[(size_t)t * N + site] : N;
        }
        f32x4 acc = {0.f, 0.f, 0.f, 0.f};
#pragma unroll
        for (int mf = 0; mf < 2; ++mf) {
            f16x8 a;
#pragma unroll
            for (int jt = 0; jt < 4; ++jt) {
                const int idx = tid[mf * 4 + jt];
                float2 f = make_float2(0.f, 0.f);
                if (idx < N) f = *(const float2*)(feats + (size_t)idx * 2);
                a[jt * 2] = (_Float16)f.x; a[jt * 2 + 1] = (_Float16)f.y;
            }
            acc = __builtin_amdgcn_mfma_f32_16x16x32_f16(a, mf ? b1 : b0, acc, 0, 0, 0);
        }
#pragma unroll
        for (int r = 0; r < 4; ++r) {
            const int row = base + q * 4 + r;
            const float v = acc[r];
            if (row < N) {
                out[(size_t)row * 16 + l15] = v;
                s += v; ss += v * v;
            }
        }
    }

    s  += __shfl_xor(s, 16);  s  += __shfl_xor(s, 32);
    ss += __shfl_xor(ss, 16); ss += __shfl_xor(ss, 32);
    __shared__ float red[4][32];
    if (lane < 16) { red[wave][l15] = s; red[wave][16 + l15] = ss; }
    __syncthreads();
    if (threadIdx.x < 32) {
        const int t2 = threadIdx.x;
        float* bank = stats_out + (blockIdx.x & (NREP - 1)) * 128;
        atomicAdd(bank + (t2 < 16 ? t2 : 48 + t2),
                  red[0][t2] + red[1][t2] + red[2][t2] + red[3][t2]);
    }
}

// ---------------------------------------------------------------------------
// Weight packing. b=0: p1 K-packed fragments. b=1..6: per-tap table
// WT[27][2][16][8] for the six 27-tap convs. b=7,8: down-conv pair fragments.
__global__ void pack_k(const float* __restrict__ w_p1, const float* __restrict__ w1,
                       const float* __restrict__ w2, const float* __restrict__ dw,
                       _Float16* __restrict__ WBp1, _Float16* __restrict__ WT27,
                       _Float16* __restrict__ WB8)
{
    const int b = blockIdx.x;
    if (b == 0) {
        for (int v = threadIdx.x; v < 2 * 64 * 8; v += 256) {
            const int mf = v >> 9, lane = (v >> 3) & 63, j = v & 7;
            const int qq = lane >> 4, n = lane & 15;
            const int kg = mf * 32 + qq * 8 + j;
            const int t = kg >> 1, cin = kg & 1;
            WBp1[v] = (t < 27) ? (_Float16)w_p1[t * 32 + cin * 16 + n] : (_Float16)0.f;
        }
    } else if (b <= 6) {
        const int ti = b - 1, lvl = ti >> 1;
        const float* src = ((ti & 1) ? w2 : w1) + lvl * 6912;
        _Float16* dst = WT27 + (size_t)ti * 6912;
        for (int v = threadIdx.x; v < 6912; v += 256) {
            const int j = v & 7, n = (v >> 3) & 15, hh = (v >> 7) & 1, t = v >> 8;
            dst[v] = (_Float16)src[t * 256 + (hh * 8 + j) * 16 + n];
        }
    } else {
        const int ti = b - 7;
        const float* src = dw + ti * 2048;
        _Float16* dst = WB8 + (size_t)ti * (4 * 64 * 8);
        for (int v = threadIdx.x; v < 4 * 64 * 8; v += 256) {
            const int p = v >> 9, lane = (v >> 3) & 63, j = v & 7;
            const int qq = lane >> 4, n = lane & 15;
            const int t = 2 * p + (qq >> 1);
            const int cin = (qq & 1) * 8 + j;
            dst[v] = (_Float16)src[t * 256 + cin * 16 + n];
        }
    }
}

// ---------------------------------------------------------------------------
// BN finalize (final 48-ch BN only): sum NREP replicas, write scale/bias.
__global__ void fin_k(float* __restrict__ stats, const float* __restrict__ g,
                      const float* __restrict__ b, float* __restrict__ sb,
                      int C, float invN)
{
    const int c = threadIdx.x;
    if (c < C) {
        float su = 0.f, sq = 0.f;
#pragma unroll
        for (int rep = 0; rep < NREP; ++rep) {
            su += stats[rep * 128 + c];
            sq += stats[rep * 128 + 64 + c];
        }
        const float mean = su * invN;
        const float var = sq * invN - mean * mean;
        const float s = g[c] * rsqrtf(var + BN_EPS);
        sb[c] = s;
        sb[64 + c] = fmaf(-mean, s, b[c]);
    }
}

// ---------------------------------------------------------------------------
__device__ __forceinline__ float wred(float v) {
#pragma unroll
    for (int off = 32; off > 0; off >>= 1) v += __shfl_xor(v, off);
    return v;
}

__global__ __launch_bounds__(256) void gstats_k(
    const float* __restrict__ R0, const float* __restrict__ R1,
    const float* __restrict__ R2, const int* __restrict__ p01,
    const int* __restrict__ p12, float* __restrict__ stats, int N0)
{
    float s[48], q[48];
#pragma unroll
    for (int c = 0; c < 48; ++c) { s[c] = 0.f; q[c] = 0.f; }

    for (int n = blockIdx.x * blockDim.x + threadIdx.x; n < N0;
         n += gridDim.x * blockDim.x) {
        const int i1 = p01[n];
        const int i2 = p12[i1];
        const float4* a0 = (const float4*)(R0 + (size_t)n * 16);
        const float4* a1 = (const float4*)(R1 + (size_t)i1 * 16);
        const float4* a2 = (const float4*)(R2 + (size_t)i2 * 16);
#pragma unroll
        for (int j = 0; j < 4; ++j) {
            const float4 v = a0[j]; const int c = 4 * j;
            s[c] += v.x; q[c] += v.x * v.x; s[c+1] += v.y; q[c+1] += v.y * v.y;
            s[c+2] += v.z; q[c+2] += v.z * v.z; s[c+3] += v.w; q[c+3] += v.w * v.w;
        }
#pragma unroll
        for (int j = 0; j < 4; ++j) {
            const float4 v = a1[j]; const int c = 16 + 4 * j;
            s[c] += v.x; q[c] += v.x * v.x; s[c+1] += v.y; q[c+1] += v.y * v.y;
            s[c+2] += v.z; q[c+2] += v.z * v.z; s[c+3] += v.w; q[c+3] += v.w * v.w;
        }
#pragma unroll
        for (int j = 0; j < 4; ++j) {
            const float4 v = a2[j]; const int c = 32 + 4 * j;
            s[c] += v.x; q[c] += v.x * v.x; s[c+1] += v.y; q[c+1] += v.y * v.y;
            s[c+2] += v.z; q[c+2] += v.z * v.z; s[c+3] += v.w; q[c+3] += v.w * v.w;
        }
    }

    __shared__ float red[4][96];
    const int wave = threadIdx.x >> 6, lane = threadIdx.x & 63;
#pragma unroll
    for (int c = 0; c < 48; ++c) {
        const float ss = wred(s[c]);
        const float qq = wred(q[c]);
        if (lane == 0) { red[wave][c] = ss; red[wave][48 + c] = qq; }
    }
    __syncthreads();
    const int t = threadIdx.x;
    if (t < 96) {
        float* bank = stats + (blockIdx.x & (NREP - 1)) * 128;
        const float v = red[0][t] + red[1][t] + red[2][t] + red[3][t];
        atomicAdd(bank + (t < 48 ? t : 64 + (t - 48)), v);
    }
}

// ---------------------------------------------------------------------------
__global__ __launch_bounds__(256) void out_k(
    const float* __restrict__ R0, const float* __restrict__ R1,
    const float* __restrict__ R2, const int* __restrict__ p01,
    const int* __restrict__ p12, const float* __restrict__ sb,
    const float* __restrict__ wsdf, const float* __restrict__ bsdf,
    float* __restrict__ out, int N0)
{
    const int n = blockIdx.x * 256 + threadIdx.x;
    if (n >= N0) return;
    const int i1 = p01[n];
    const int i2 = p12[i1];
    float acc = bsdf[0];
    const float4* a0 = (const float4*)(R0 + (size_t)n * 16);
    const float4* a1 = (const float4*)(R1 + (size_t)i1 * 16);
    const float4* a2 = (const float4*)(R2 + (size_t)i2 * 16);
#pragma unroll
    for (int j = 0; j < 4; ++j) {
        const float4 v = a0[j]; const int c = 4 * j;
        acc += fmaxf(fmaf(v.x, sb[c+0], sb[64+c+0]), 0.f) * wsdf[c+0];
        acc += fmaxf(fmaf(v.y, sb[c+1], sb[64+c+1]), 0.f) * wsdf[c+1];
        acc += fmaxf(fmaf(v.z, sb[c+2], sb[64+c+2]), 0.f) * wsdf[c+2];
        acc += fmaxf(fmaf(v.w, sb[c+3], sb[64+c+3]), 0.f) * wsdf[c+3];
    }
#pragma unroll
    for (int j = 0; j < 4; ++j) {
        const float4 v = a1[j]; const int c = 16 + 4 * j;
        acc += fmaxf(fmaf(v.x, sb[c+0], sb[64+c+0]), 0.f) * wsdf[c+0];
        acc += fmaxf(fmaf(v.y, sb[c+1], sb[64+c+1]), 0.f) * wsdf[c+1];
        acc += fmaxf(fmaf(v.z, sb[c+2], sb[64+c+2]), 0.f) * wsdf[c+2];
        acc += fmaxf(fmaf(v.w, sb[c+3], sb[64+c+3]), 0.f) * wsdf[c+3];
    }
#pragma unroll
    for (int j = 0; j < 4; ++j) {
        const float4 v = a2[j]; const int c = 32 + 4 * j;
        acc += fmaxf(fmaf(v.x, sb[c+0], sb[64+c+0]), 0.f) * wsdf[c+0];
        acc += fmaxf(fmaf(v.y, sb[c+1], sb[64+c+1]), 0.f) * wsdf[c+1];
        acc += fmaxf(fmaf(v.z, sb[c+2], sb[64+c+2]), 0.f) * wsdf[c+2];
        acc += fmaxf(fmaf(v.w, sb[c+3], sb[64+c+3]), 0.f) * wsdf[c+3];
    }
    out[n] = acc;
}

// ---------------------------------------------------------------------------
extern "C" void kernel_launch(void* const* d_in, const int* in_sizes, int n_in,
                              void* d_out, int out_size, void* d_ws, size_t ws_size,
                              hipStream_t stream)
{
    const float* feats = (const float*)d_in[0];
    const float* w_p1  = (const float*)d_in[1];
    const float* bn1g  = (const float*)d_in[2];
    const float* bn1b  = (const float*)d_in[3];
    const float* w1    = (const float*)d_in[4];
    const float* bn2g  = (const float*)d_in[5];
    const float* bn2b  = (const float*)d_in[6];
    const float* w2    = (const float*)d_in[7];
    const float* dbng  = (const float*)d_in[8];
    const float* dbnb  = (const float*)d_in[9];
    const float* dw    = (const float*)d_in[10];
    const float* bn3g  = (const float*)d_in[11];
    const float* bn3b  = (const float*)d_in[12];
    const float* wsdf  = (const float*)d_in[13];
    const float* bsdf  = (const float*)d_in[14];
    const int* nbr0    = (const int*)d_in[15];
    const int* nbr1    = (const int*)d_in[16];
    const int* nbr2    = (const int*)d_in[17];
    const int* down01  = (const int*)d_in[18];
    const int* down12  = (const int*)d_in[19];
    const int* p01     = (const int*)d_in[20];
    const int* p12     = (const int*)d_in[21];

    const int N0 = in_sizes[0] / 2;
    const int N1 = in_sizes[18] / 8;
    const int N2 = in_sizes[19] / 8;
    const int ng0 = (N0 + 15) / 16, ng1 = (N1 + 15) / 16, ng2 = (N2 + 15) / 16;
    const int maxe = ng0 * 27 + 64;  // fixed-stride slots

    // workspace carve-up (256B aligned segments)
    char* wp = (char*)d_ws;
    auto alloc = [&](size_t bytes) { char* r = wp; wp += (bytes + 255) & ~(size_t)255; return r; };
    float* T  = (float*)alloc((size_t)N0 * 16 * 4);
    float* R0 = (float*)alloc((size_t)N0 * 16 * 4);
    float* R1 = (float*)alloc((size_t)N1 * 16 * 4);
    float* R2 = (float*)alloc((size_t)N2 * 16 * 4);
    float* st = (float*)alloc(9 * NREP * 128 * 4);
    float* sb = (float*)alloc(128 * 4);
    _Float16* WBp1 = (_Float16*)alloc(2 * 64 * 8 * 2);
    _Float16* WT27 = (_Float16*)alloc(6 * 6912 * 2);
    _Float16* WB8  = (_Float16*)alloc(2 * 4 * 64 * 8 * 2);
    int* gcnt = (int*)alloc((size_t)ng0 * 4);
    int* ent  = (int*)alloc((size_t)maxe * 16 * 4);

    hipMemsetAsync(st, 0, 9 * NREP * 128 * sizeof(float), stream);

    const dim3 B(256);
    auto cgrid = [](int n) {  // persistent grids: <=4096 blocks, 4 waves each
        const int g = (((n + 15) / 16) + 3) / 4;
        return dim3((unsigned)(g < 4096 ? g : 4096));
    };
    auto lgrid = [](int n) { return dim3((unsigned)((n + 255) / 256)); };
    const float i0 = 1.0f / N0, i1 = 1.0f / N1, i2 = 1.0f / N2;
    auto S = [&](int i) { return st + i * NREP * 128; };
    auto WT = [&](int i) { return WT27 + (size_t)i * 6912; };
    auto W8 = [&](int i) { return WB8 + (size_t)i * (4 * 64 * 8); };

    pack_k<<<9, B, 0, stream>>>(w_p1, w1, w2, dw, WBp1, WT27, WB8);

    // ---- level 0 ----
    build_k<<<cgrid(N0), B, 0, stream>>>(nbr0, N0, N0, ng0, gcnt, ent);
    convp1_k<<<cgrid(N0), B, 0, stream>>>(feats, nbr0, WBp1, R0, S(0), N0);
    conv16c_k<<<cgrid(N0), B, 0, stream>>>(R0, gcnt, ent, WT(0), bn1g, bn1b,
                                           S(0), i0, T, S(1), N0, N0, 0);
    conv16c_k<<<cgrid(N0), B, 0, stream>>>(T, gcnt, ent, WT(1), bn2g, bn2b,
                                           S(1), i0, R0, S(2), N0, N0, 1);
    conv16_k<8><<<cgrid(N1), B, 0, stream>>>(R0, down01, W8(0), dbng, dbnb,
                                             S(2), i0, R1, S(3), N1, N0, 0);

    // ---- level 1 (rebuild compact rulebook in-place; stream-serial) ----
    build_k<<<cgrid(N1), B, 0, stream>>>(nbr1, N1, N1, ng1, gcnt, ent);
    conv16c_k<<<cgrid(N1), B, 0, stream>>>(R1, gcnt, ent, WT(2), bn1g + 16, bn1b + 16,
                                           S(3), i1, T, S(4), N1, N1, 0);
    conv16c_k<<<cgrid(N1), B, 0, stream>>>(T, gcnt, ent, WT(3), bn2g + 16, bn2b + 16,
                                           S(4), i1, R1, S(5), N1, N1, 1);
    conv16_k<8><<<cgrid(N2), B, 0, stream>>>(R1, down12, W8(1), dbng + 16, dbnb + 16,
                                             S(5), i1, R2, S(6), N2, N1, 0);

    // ---- level 2 ----
    build_k<<<cgrid(N2), B, 0, stream>>>(nbr2, N2, N2, ng2, gcnt, ent);
    conv16c_k<<<cgrid(N2), B, 0, stream>>>(R2, gcnt, ent, WT(4), bn1g + 32, bn1b + 32,
                                           S(6), i2, T, S(7), N2, N2, 0);
    conv16c_k<<<cgrid(N2), B, 0, stream>>>(T, gcnt, ent, WT(5), bn2g + 32, bn2b + 32,
                                           S(7), i2, R2, nullptr, N2, N2, 1);

    // ---- final concat + BN48 + ReLU + linear ----
    gstats_k<<<512, B, 0, stream>>>(R0, R1, R2, p01, p12, S(8), N0);
    fin_k<<<1, 64, 0, stream>>>(S(8), bn3g, bn3b, sb, 48, i0);
    out_k<<<lgrid(N0), B, 0, stream>>>(R0, R1, R2, p01, p12, sb, wsdf, bsdf,
                                       (float*)d_out, N0);
}

// Round 17
// 634.015 us; speedup vs baseline: 1.0499x; 1.0499x over previous
//
#include <hip/hip_runtime.h>

#define BN_EPS 1e-4f
#define NREP 16  // stats replica banks (atomic-contention spreading)

typedef _Float16 f16x8 __attribute__((ext_vector_type(8)));
typedef __fp16 h8 __attribute__((ext_vector_type(8)));
typedef __fp16 h2 __attribute__((ext_vector_type(2)));
typedef float f32x4 __attribute__((ext_vector_type(4)));

// ---------------------------------------------------------------------------
// Build group-compacted rulebook, fixed-stride slots, byte-offset packing:
//   ent[(grp*27+e)*16 + l] = (idx << 5) | tap ; gcnt[grp] = active tap count.
__global__ __launch_bounds__(256) void build_k(
    const int* __restrict__ nbr, int N, int Nin, int ngroups,
    int* __restrict__ gcnt, int* __restrict__ ent)
{
    const int wave = threadIdx.x >> 6, lane = threadIdx.x & 63;
    const int l15 = lane & 15, q = lane >> 4;

    for (int grp = blockIdx.x * 4 + wave; grp < ngroups; grp += gridDim.x * 4) {
        const int site = grp * 16 + l15;
        int v[7];
        unsigned act = 0;
#pragma unroll
        for (int p = 0; p < 7; ++p) {
            const int t = 4 * p + q;
            int idx = Nin;
            if (t < 27 && site < N) idx = nbr[(size_t)t * N + site];
            v[p] = idx;
            const unsigned long long bal = __ballot(idx < Nin);
#pragma unroll
            for (int qq = 0; qq < 4; ++qq) {
                const int tt = 4 * p + qq;
                if (tt < 27 && ((bal >> (16 * qq)) & 0xFFFFull)) act |= 1u << tt;
            }
        }
        const int cnt = __popc(act);
        if (lane == 0) gcnt[grp] = cnt;
        const int e0 = grp * 27;
#pragma unroll
        for (int p = 0; p < 7; ++p) {
            const int t = 4 * p + q;
            if (t < 27 && ((act >> t) & 1)) {
                const int e = __popc(act & ((1u << t) - 1));   // rank
                ent[(size_t)(e0 + e) * 16 + l15] = (v[p] << 5) | t;
            }
        }
    }
}

// ---------------------------------------------------------------------------
// MFMA conv over the compacted rulebook, CIN=16.
// R17: gathers from a PRE-BN FP16 MIRROR of the previous conv's output —
// 32B rows -> ONE 16B load per pair-slot lane (was 2x16B fp32), halving
// gather fetch + inst count. BN+ReLU applied in packed fp16 (8 VALU/gather,
// no cvt). R14's straightline gather->MFMA loop (best-known schedule; the
// explicit stages of R13/R15/R16 all spilled or regressed).
// Epilogue: fp32 out (skip/stats/final layers) + coalesced fp16 mirror write.
__global__ __launch_bounds__(256, 4) void conv16c_k(
    const __fp16* __restrict__ H,       // [Nin, 16] fp16 PRE-BN mirror
    const int* __restrict__ gcnt,       // [ngroups]
    const int* __restrict__ ent,        // [ngroups*27][16] packed
    const _Float16* __restrict__ WT,    // [27][2][16][8] per-tap B table
    const float* __restrict__ g,        // [16] BN gamma (input BN)
    const float* __restrict__ b,        // [16] BN beta
    const float* __restrict__ stats_in, // [NREP][128] stats of fp32 out
    float invN,
    float* __restrict__ out,            // [Nout, 16] fp32
    __fp16* __restrict__ Hout,          // [Nout, 16] fp16 mirror or nullptr
    float* __restrict__ stats_out,      // [NREP][128] or nullptr
    int Nout, int Nin, int addSkip)
{
    __shared__ _Float16 WTs[27 * 2 * 16 * 8];  // 13824 B
    __shared__ float TRS[4][16 * 20];          // 5120 B
    __shared__ float RED[4][32];               // 512 B
    __shared__ float sbl[2][16];               // 128 B

    const int wave = threadIdx.x >> 6, lane = threadIdx.x & 63;
    const int l15 = lane & 15, q = lane >> 4;
    const int h = q & 1, th = q >> 1;
    const int SENT = Nin << 5;
    float* Tr = TRS[wave];

    {   // stage per-tap B table to LDS + compute BN scale/bias (once/block)
        const float4* s = (const float4*)WT;
        float4* d = (float4*)WTs;
        for (int v = threadIdx.x; v < 27 * 2 * 16; v += 256) d[v] = s[v];
        if (threadIdx.x < 16) {
            const int c = threadIdx.x;
            float su = 0.f, sq = 0.f;
#pragma unroll
            for (int rep = 0; rep < NREP; ++rep) {
                su += stats_in[rep * 128 + c];
                sq += stats_in[rep * 128 + 64 + c];
            }
            const float mean = su * invN;
            const float var = sq * invN - mean * mean;
            const float sc = g[c] * rsqrtf(var + BN_EPS);
            sbl[0][c] = sc;
            sbl[1][c] = fmaf(-mean, sc, b[c]);
        }
    }
    __syncthreads();

    h8 sc8, bi8;
    const h8 z8 = {};
#pragma unroll
    for (int j = 0; j < 8; ++j) {
        sc8[j] = (__fp16)sbl[0][h * 8 + j];
        bi8[j] = (__fp16)sbl[1][h * 8 + j];
    }

    const int ngroups = (Nout + 15) >> 4;
    const int stride = gridDim.x * 4;
    const int rr = lane >> 2, cc = (lane & 3) * 4;
    float sj[4] = {0.f, 0.f, 0.f, 0.f}, qj[4] = {0.f, 0.f, 0.f, 0.f};

    int grp = blockIdx.x * 4 + wave;
    int cc_cur = 0, cc_nxt = 0;
    int pe[14];
    if (grp < ngroups) {
        cc_cur = gcnt[grp];
        const int g1 = grp + stride;
        if (g1 < ngroups) cc_nxt = gcnt[g1];
        const size_t e0 = (size_t)grp * 27;
#pragma unroll
        for (int pp = 0; pp < 14; ++pp) {
            const int sidx = 2 * pp + th;
            int r = SENT;
            if (sidx < cc_cur) r = ent[(e0 + sidx) * 16 + l15];
            pe[pp] = r;
        }
    }

    while (grp < ngroups) {
        int ce[14];
#pragma unroll
        for (int pp = 0; pp < 14; ++pp) ce[pp] = pe[pp];

        const int base = grp * 16, srow = base + rr;
        float4 skip = make_float4(0.f, 0.f, 0.f, 0.f);
        if (addSkip && srow < Nout)
            skip = *(const float4*)(out + (size_t)srow * 16 + cc);

        const int gn = grp + stride;
        int cc_nn = 0;
        if (gn < ngroups) {
            const size_t e0n = (size_t)gn * 27;
#pragma unroll
            for (int pp = 0; pp < 14; ++pp) {
                const int sidx = 2 * pp + th;
                int r = SENT;
                if (sidx < cc_nxt) r = ent[(e0n + sidx) * 16 + l15];
                pe[pp] = r;
            }
            const int gnn = gn + stride;
            if (gnn < ngroups) cc_nn = gcnt[gnn];
        }

        // ---- straightline gather (one 16B fp16 load) + fp16 BN + MFMA
        f32x4 acc0 = {0.f, 0.f, 0.f, 0.f}, acc1 = {0.f, 0.f, 0.f, 0.f};
#pragma unroll
        for (int pp = 0; pp < 14; ++pp) {
            const int raw = ce[pp];
            const int tap = raw & 31;
            h8 ah = {};
            if (raw < SENT) {                 // exec-masked gather
                ah = *(const h8*)((const char*)H + (raw & ~31) + h * 16);
                ah = __builtin_elementwise_max(ah * sc8 + bi8, z8);
            }
            const f16x8 a = __builtin_bit_cast(f16x8, ah);
            const f16x8 bb = *(const f16x8*)(WTs + ((tap * 2 + h) * 16 + l15) * 8);
            if (pp & 1) acc1 = __builtin_amdgcn_mfma_f32_16x16x32_f16(a, bb, acc1, 0, 0, 0);
            else        acc0 = __builtin_amdgcn_mfma_f32_16x16x32_f16(a, bb, acc0, 0, 0, 0);
        }

#pragma unroll
        for (int r = 0; r < 4; ++r)
            Tr[(q * 4 + r) * 20 + l15] = acc0[r] + acc1[r];
        float4 v4;
        v4.x = Tr[rr * 20 + cc + 0] + skip.x;
        v4.y = Tr[rr * 20 + cc + 1] + skip.y;
        v4.z = Tr[rr * 20 + cc + 2] + skip.z;
        v4.w = Tr[rr * 20 + cc + 3] + skip.w;
        if (srow < Nout) {
            *(float4*)(out + (size_t)srow * 16 + cc) = v4;
            if (Hout) {                       // coalesced fp16 mirror (8B/lane)
                h2* hp = (h2*)(Hout + (size_t)srow * 16 + cc);
                hp[0] = __builtin_amdgcn_cvt_pkrtz(v4.x, v4.y);
                hp[1] = __builtin_amdgcn_cvt_pkrtz(v4.z, v4.w);
            }
            sj[0] += v4.x; qj[0] += v4.x * v4.x;
            sj[1] += v4.y; qj[1] += v4.y * v4.y;
            sj[2] += v4.z; qj[2] += v4.z * v4.z;
            sj[3] += v4.w; qj[3] += v4.w * v4.w;
        }
        cc_cur = cc_nxt; cc_nxt = cc_nn;
        grp = gn;
    }

    if (stats_out) {  // uniform branch (kernel arg)
#pragma unroll
        for (int m = 4; m < 64; m <<= 1) {
#pragma unroll
            for (int j = 0; j < 4; ++j) {
                sj[j] += __shfl_xor(sj[j], m);
                qj[j] += __shfl_xor(qj[j], m);
            }
        }
        if (lane < 4) {
#pragma unroll
            for (int j = 0; j < 4; ++j) {
                RED[wave][lane * 4 + j] = sj[j];
                RED[wave][16 + lane * 4 + j] = qj[j];
            }
        }
        __syncthreads();
        if (threadIdx.x < 32) {
            const int t2 = threadIdx.x;
            float* bank = stats_out + (blockIdx.x & (NREP - 1)) * 128;
            atomicAdd(bank + (t2 < 16 ? t2 : 48 + t2),
                      RED[0][t2] + RED[1][t2] + RED[2][t2] + RED[3][t2]);
        }
    }
}

// ---------------------------------------------------------------------------
// Dense-rulebook conv (K=8 down-convs): fp16-mirror gathers + fp16 BN.
template <int K>
__global__ __launch_bounds__(256, 4) void conv16_k(
    const __fp16* __restrict__ H, const int* __restrict__ nbr,
    const _Float16* __restrict__ WB,
    const float* __restrict__ g, const float* __restrict__ b,
    const float* __restrict__ stats_in, float invN,
    float* __restrict__ out, __fp16* __restrict__ Hout,
    float* __restrict__ stats_out, int Nout, int Nin, int addSkip)
{
    constexpr int PAIRS = (K + 1) / 2;
    __shared__ float sbl[2][16];
    const int wave = threadIdx.x >> 6, lane = threadIdx.x & 63;
    const int l15 = lane & 15, q = lane >> 4;
    const int h = q & 1, th = q >> 1;

    if (threadIdx.x < 16) {
        const int c = threadIdx.x;
        float su = 0.f, sq = 0.f;
#pragma unroll
        for (int rep = 0; rep < NREP; ++rep) {
            su += stats_in[rep * 128 + c];
            sq += stats_in[rep * 128 + 64 + c];
        }
        const float mean = su * invN;
        const float var = sq * invN - mean * mean;
        const float sc = g[c] * rsqrtf(var + BN_EPS);
        sbl[0][c] = sc;
        sbl[1][c] = fmaf(-mean, sc, b[c]);
    }
    __syncthreads();

    h8 sc8, bi8;
    const h8 z8 = {};
#pragma unroll
    for (int j = 0; j < 8; ++j) {
        sc8[j] = (__fp16)sbl[0][h * 8 + j];
        bi8[j] = (__fp16)sbl[1][h * 8 + j];
    }

    f16x8 bfr[PAIRS];
#pragma unroll
    for (int p = 0; p < PAIRS; ++p)
        bfr[p] = *(const f16x8*)(WB + ((size_t)p * 64 + lane) * 8);

    const int ngroups = (Nout + 15) >> 4;
    float s = 0.f, ss = 0.f;

    for (int grp = blockIdx.x * 4 + wave; grp < ngroups; grp += gridDim.x * 4) {
        const int base = grp * 16;
        const int site = min(base + l15, Nout - 1);
        int idxs[PAIRS];
#pragma unroll
        for (int p = 0; p < PAIRS; ++p) {
            const int t = 2 * p + ((2 * p + 1 < K) ? th : 0);
            idxs[p] = nbr[(size_t)t * Nout + site];
        }
        f32x4 acc0 = {0.f, 0.f, 0.f, 0.f}, acc1 = {0.f, 0.f, 0.f, 0.f};
#pragma unroll
        for (int p = 0; p < PAIRS; ++p) {
            const int idx = idxs[p];
            h8 ah = {};
            if (idx < Nin) {
                ah = *(const h8*)(H + (size_t)idx * 16 + h * 8);
                ah = __builtin_elementwise_max(ah * sc8 + bi8, z8);
            }
            const f16x8 a = __builtin_bit_cast(f16x8, ah);
            if (p & 1) acc1 = __builtin_amdgcn_mfma_f32_16x16x32_f16(a, bfr[p], acc1, 0, 0, 0);
            else       acc0 = __builtin_amdgcn_mfma_f32_16x16x32_f16(a, bfr[p], acc0, 0, 0, 0);
        }
#pragma unroll
        for (int r = 0; r < 4; ++r) {
            const int row = base + q * 4 + r;
            float v = acc0[r] + acc1[r];
            if (row < Nout) {
                float* op = out + (size_t)row * 16 + l15;
                if (addSkip) v += *op;
                *op = v;
                if (Hout) Hout[(size_t)row * 16 + l15] = (__fp16)v;
                s += v; ss += v * v;
            }
        }
    }

    if (stats_out) {
        s  += __shfl_xor(s, 16);  s  += __shfl_xor(s, 32);
        ss += __shfl_xor(ss, 16); ss += __shfl_xor(ss, 32);
        __shared__ float red[4][32];
        if (lane < 16) { red[wave][l15] = s; red[wave][16 + l15] = ss; }
        __syncthreads();
        if (threadIdx.x < 32) {
            const int t2 = threadIdx.x;
            float* bank = stats_out + (blockIdx.x & (NREP - 1)) * 128;
            atomicAdd(bank + (t2 < 16 ? t2 : 48 + t2),
                      red[0][t2] + red[1][t2] + red[2][t2] + red[3][t2]);
        }
    }
}

// ---------------------------------------------------------------------------
// p1 conv (CIN=2): gathers raw fp32 feats (cvt in register), masked.
// Writes fp32 out + fp16 mirror.
__global__ __launch_bounds__(256, 4) void convp1_k(
    const float* __restrict__ feats,    // [N0, 2] fp32
    const int* __restrict__ nbr,        // [27, N0]
    const _Float16* __restrict__ WB,    // [2][64][8]
    float* __restrict__ out, __fp16* __restrict__ Hout,
    float* __restrict__ stats_out, int N)
{
    const int wave = threadIdx.x >> 6, lane = threadIdx.x & 63;
    const int l15 = lane & 15, q = lane >> 4;

    f16x8 b0 = *(const f16x8*)(WB + (size_t)lane * 8);
    f16x8 b1 = *(const f16x8*)(WB + ((size_t)64 + lane) * 8);

    const int ngroups = (N + 15) >> 4;
    float s = 0.f, ss = 0.f;

    for (int grp = blockIdx.x * 4 + wave; grp < ngroups; grp += gridDim.x * 4) {
        const int base = grp * 16;
        const int site = min(base + l15, N - 1);
        int tid[8];
#pragma unroll
        for (int u = 0; u < 8; ++u) {
            const int t = (u < 4) ? (q * 4 + u) : (16 + q * 4 + (u - 4));
            tid[u] = (t < 27) ? nbr[(size_t)t * N + site] : N;
        }
        f32x4 acc = {0.f, 0.f, 0.f, 0.f};
#pragma unroll
        for (int mf = 0; mf < 2; ++mf) {
            f16x8 a;
#pragma unroll
            for (int jt = 0; jt < 4; ++jt) {
                const int idx = tid[mf * 4 + jt];
                float2 f = make_float2(0.f, 0.f);
                if (idx < N) f = *(const float2*)(feats + (size_t)idx * 2);
                a[jt * 2] = (_Float16)f.x; a[jt * 2 + 1] = (_Float16)f.y;
            }
            acc = __builtin_amdgcn_mfma_f32_16x16x32_f16(a, mf ? b1 : b0, acc, 0, 0, 0);
        }
#pragma unroll
        for (int r = 0; r < 4; ++r) {
            const int row = base + q * 4 + r;
            const float v = acc[r];
            if (row < N) {
                out[(size_t)row * 16 + l15] = v;
                Hout[(size_t)row * 16 + l15] = (__fp16)v;
                s += v; ss += v * v;
            }
        }
    }

    s  += __shfl_xor(s, 16);  s  += __shfl_xor(s, 32);
    ss += __shfl_xor(ss, 16); ss += __shfl_xor(ss, 32);
    __shared__ float red[4][32];
    if (lane < 16) { red[wave][l15] = s; red[wave][16 + l15] = ss; }
    __syncthreads();
    if (threadIdx.x < 32) {
        const int t2 = threadIdx.x;
        float* bank = stats_out + (blockIdx.x & (NREP - 1)) * 128;
        atomicAdd(bank + (t2 < 16 ? t2 : 48 + t2),
                  red[0][t2] + red[1][t2] + red[2][t2] + red[3][t2]);
    }
}

// ---------------------------------------------------------------------------
// Weight packing. b=0: p1 K-packed fragments. b=1..6: per-tap table
// WT[27][2][16][8] for the six 27-tap convs. b=7,8: down-conv pair fragments.
__global__ void pack_k(const float* __restrict__ w_p1, const float* __restrict__ w1,
                       const float* __restrict__ w2, const float* __restrict__ dw,
                       _Float16* __restrict__ WBp1, _Float16* __restrict__ WT27,
                       _Float16* __restrict__ WB8)
{
    const int b = blockIdx.x;
    if (b == 0) {
        for (int v = threadIdx.x; v < 2 * 64 * 8; v += 256) {
            const int mf = v >> 9, lane = (v >> 3) & 63, j = v & 7;
            const int qq = lane >> 4, n = lane & 15;
            const int kg = mf * 32 + qq * 8 + j;
            const int t = kg >> 1, cin = kg & 1;
            WBp1[v] = (t < 27) ? (_Float16)w_p1[t * 32 + cin * 16 + n] : (_Float16)0.f;
        }
    } else if (b <= 6) {
        const int ti = b - 1, lvl = ti >> 1;
        const float* src = ((ti & 1) ? w2 : w1) + lvl * 6912;
        _Float16* dst = WT27 + (size_t)ti * 6912;
        for (int v = threadIdx.x; v < 6912; v += 256) {
            const int j = v & 7, n = (v >> 3) & 15, hh = (v >> 7) & 1, t = v >> 8;
            dst[v] = (_Float16)src[t * 256 + (hh * 8 + j) * 16 + n];
        }
    } else {
        const int ti = b - 7;
        const float* src = dw + ti * 2048;
        _Float16* dst = WB8 + (size_t)ti * (4 * 64 * 8);
        for (int v = threadIdx.x; v < 4 * 64 * 8; v += 256) {
            const int p = v >> 9, lane = (v >> 3) & 63, j = v & 7;
            const int qq = lane >> 4, n = lane & 15;
            const int t = 2 * p + (qq >> 1);
            const int cin = (qq & 1) * 8 + j;
            dst[v] = (_Float16)src[t * 256 + cin * 16 + n];
        }
    }
}

// ---------------------------------------------------------------------------
// BN finalize (final 48-ch BN only): sum NREP replicas, write scale/bias.
__global__ void fin_k(float* __restrict__ stats, const float* __restrict__ g,
                      const float* __restrict__ b, float* __restrict__ sb,
                      int C, float invN)
{
    const int c = threadIdx.x;
    if (c < C) {
        float su = 0.f, sq = 0.f;
#pragma unroll
        for (int rep = 0; rep < NREP; ++rep) {
            su += stats[rep * 128 + c];
            sq += stats[rep * 128 + 64 + c];
        }
        const float mean = su * invN;
        const float var = sq * invN - mean * mean;
        const float s = g[c] * rsqrtf(var + BN_EPS);
        sb[c] = s;
        sb[64 + c] = fmaf(-mean, s, b[c]);
    }
}

// ---------------------------------------------------------------------------
__device__ __forceinline__ float wred(float v) {
#pragma unroll
    for (int off = 32; off > 0; off >>= 1) v += __shfl_xor(v, off);
    return v;
}

__global__ __launch_bounds__(256) void gstats_k(
    const float* __restrict__ R0, const float* __restrict__ R1,
    const float* __restrict__ R2, const int* __restrict__ p01,
    const int* __restrict__ p12, float* __restrict__ stats, int N0)
{
    float s[48], q[48];
#pragma unroll
    for (int c = 0; c < 48; ++c) { s[c] = 0.f; q[c] = 0.f; }

    for (int n = blockIdx.x * blockDim.x + threadIdx.x; n < N0;
         n += gridDim.x * blockDim.x) {
        const int i1 = p01[n];
        const int i2 = p12[i1];
        const float4* a0 = (const float4*)(R0 + (size_t)n * 16);
        const float4* a1 = (const float4*)(R1 + (size_t)i1 * 16);
        const float4* a2 = (const float4*)(R2 + (size_t)i2 * 16);
#pragma unroll
        for (int j = 0; j < 4; ++j) {
            const float4 v = a0[j]; const int c = 4 * j;
            s[c] += v.x; q[c] += v.x * v.x; s[c+1] += v.y; q[c+1] += v.y * v.y;
            s[c+2] += v.z; q[c+2] += v.z * v.z; s[c+3] += v.w; q[c+3] += v.w * v.w;
        }
#pragma unroll
        for (int j = 0; j < 4; ++j) {
            const float4 v = a1[j]; const int c = 16 + 4 * j;
            s[c] += v.x; q[c] += v.x * v.x; s[c+1] += v.y; q[c+1] += v.y * v.y;
            s[c+2] += v.z; q[c+2] += v.z * v.z; s[c+3] += v.w; q[c+3] += v.w * v.w;
        }
#pragma unroll
        for (int j = 0; j < 4; ++j) {
            const float4 v = a2[j]; const int c = 32 + 4 * j;
            s[c] += v.x; q[c] += v.x * v.x; s[c+1] += v.y; q[c+1] += v.y * v.y;
            s[c+2] += v.z; q[c+2] += v.z * v.z; s[c+3] += v.w; q[c+3] += v.w * v.w;
        }
    }

    __shared__ float red[4][96];
    const int wave = threadIdx.x >> 6, lane = threadIdx.x & 63;
#pragma unroll
    for (int c = 0; c < 48; ++c) {
        const float ss = wred(s[c]);
        const float qq = wred(q[c]);
        if (lane == 0) { red[wave][c] = ss; red[wave][48 + c] = qq; }
    }
    __syncthreads();
    const int t = threadIdx.x;
    if (t < 96) {
        float* bank = stats + (blockIdx.x & (NREP - 1)) * 128;
        const float v = red[0][t] + red[1][t] + red[2][t] + red[3][t];
        atomicAdd(bank + (t < 48 ? t : 64 + (t - 48)), v);
    }
}

// ---------------------------------------------------------------------------
__global__ __launch_bounds__(256) void out_k(
    const float* __restrict__ R0, const float* __restrict__ R1,
    const float* __restrict__ R2, const int* __restrict__ p01,
    const int* __restrict__ p12, const float* __restrict__ sb,
    const float* __restrict__ wsdf, const float* __restrict__ bsdf,
    float* __restrict__ out, int N0)
{
    const int n = blockIdx.x * 256 + threadIdx.x;
    if (n >= N0) return;
    const int i1 = p01[n];
    const int i2 = p12[i1];
    float acc = bsdf[0];
    const float4* a0 = (const float4*)(R0 + (size_t)n * 16);
    const float4* a1 = (const float4*)(R1 + (size_t)i1 * 16);
    const float4* a2 = (const float4*)(R2 + (size_t)i2 * 16);
#pragma unroll
    for (int j = 0; j < 4; ++j) {
        const float4 v = a0[j]; const int c = 4 * j;
        acc += fmaxf(fmaf(v.x, sb[c+0], sb[64+c+0]), 0.f) * wsdf[c+0];
        acc += fmaxf(fmaf(v.y, sb[c+1], sb[64+c+1]), 0.f) * wsdf[c+1];
        acc += fmaxf(fmaf(v.z, sb[c+2], sb[64+c+2]), 0.f) * wsdf[c+2];
        acc += fmaxf(fmaf(v.w, sb[c+3], sb[64+c+3]), 0.f) * wsdf[c+3];
    }
#pragma unroll
    for (int j = 0; j < 4; ++j) {
        const float4 v = a1[j]; const int c = 16 + 4 * j;
        acc += fmaxf(fmaf(v.x, sb[c+0], sb[64+c+0]), 0.f) * wsdf[c+0];
        acc += fmaxf(fmaf(v.y, sb[c+1], sb[64+c+1]), 0.f) * wsdf[c+1];
        acc += fmaxf(fmaf(v.z, sb[c+2], sb[64+c+2]), 0.f) * wsdf[c+2];
        acc += fmaxf(fmaf(v.w, sb[c+3], sb[64+c+3]), 0.f) * wsdf[c+3];
    }
#pragma unroll
    for (int j = 0; j < 4; ++j) {
        const float4 v = a2[j]; const int c = 32 + 4 * j;
        acc += fmaxf(fmaf(v.x, sb[c+0], sb[64+c+0]), 0.f) * wsdf[c+0];
        acc += fmaxf(fmaf(v.y, sb[c+1], sb[64+c+1]), 0.f) * wsdf[c+1];
        acc += fmaxf(fmaf(v.z, sb[c+2], sb[64+c+2]), 0.f) * wsdf[c+2];
        acc += fmaxf(fmaf(v.w, sb[c+3], sb[64+c+3]), 0.f) * wsdf[c+3];
    }
    out[n] = acc;
}

// ---------------------------------------------------------------------------
extern "C" void kernel_launch(void* const* d_in, const int* in_sizes, int n_in,
                              void* d_out, int out_size, void* d_ws, size_t ws_size,
                              hipStream_t stream)
{
    const float* feats = (const float*)d_in[0];
    const float* w_p1  = (const float*)d_in[1];
    const float* bn1g  = (const float*)d_in[2];
    const float* bn1b  = (const float*)d_in[3];
    const float* w1    = (const float*)d_in[4];
    const float* bn2g  = (const float*)d_in[5];
    const float* bn2b  = (const float*)d_in[6];
    const float* w2    = (const float*)d_in[7];
    const float* dbng  = (const float*)d_in[8];
    const float* dbnb  = (const float*)d_in[9];
    const float* dw    = (const float*)d_in[10];
    const float* bn3g  = (const float*)d_in[11];
    const float* bn3b  = (const float*)d_in[12];
    const float* wsdf  = (const float*)d_in[13];
    const float* bsdf  = (const float*)d_in[14];
    const int* nbr0    = (const int*)d_in[15];
    const int* nbr1    = (const int*)d_in[16];
    const int* nbr2    = (const int*)d_in[17];
    const int* down01  = (const int*)d_in[18];
    const int* down12  = (const int*)d_in[19];
    const int* p01     = (const int*)d_in[20];
    const int* p12     = (const int*)d_in[21];

    const int N0 = in_sizes[0] / 2;
    const int N1 = in_sizes[18] / 8;
    const int N2 = in_sizes[19] / 8;
    const int ng0 = (N0 + 15) / 16, ng1 = (N1 + 15) / 16, ng2 = (N2 + 15) / 16;
    const int maxe = ng0 * 27 + 64;  // fixed-stride slots

    // workspace carve-up (256B aligned segments)
    char* wp = (char*)d_ws;
    auto alloc = [&](size_t bytes) { char* r = wp; wp += (bytes + 255) & ~(size_t)255; return r; };
    float* T  = (float*)alloc((size_t)N0 * 16 * 4);
    float* R0 = (float*)alloc((size_t)N0 * 16 * 4);
    float* R1 = (float*)alloc((size_t)N1 * 16 * 4);
    float* R2 = (float*)alloc((size_t)N2 * 16 * 4);
    __fp16* HA = (__fp16*)alloc((size_t)(N0 + 16) * 16 * 2);
    __fp16* HB = (__fp16*)alloc((size_t)(N0 + 16) * 16 * 2);
    float* st = (float*)alloc(9 * NREP * 128 * 4);
    float* sb = (float*)alloc(128 * 4);
    _Float16* WBp1 = (_Float16*)alloc(2 * 64 * 8 * 2);
    _Float16* WT27 = (_Float16*)alloc(6 * 6912 * 2);
    _Float16* WB8  = (_Float16*)alloc(2 * 4 * 64 * 8 * 2);
    int* gcnt = (int*)alloc((size_t)ng0 * 4);
    int* ent  = (int*)alloc((size_t)maxe * 16 * 4);

    hipMemsetAsync(st, 0, 9 * NREP * 128 * sizeof(float), stream);

    const dim3 B(256);
    auto cgrid = [](int n) {  // persistent grids: <=2048 blocks, 4 waves each
        const int g = (((n + 15) / 16) + 3) / 4;
        return dim3((unsigned)(g < 2048 ? g : 2048));
    };
    auto lgrid = [](int n) { return dim3((unsigned)((n + 255) / 256)); };
    const float i0 = 1.0f / N0, i1 = 1.0f / N1, i2 = 1.0f / N2;
    auto S = [&](int i) { return st + i * NREP * 128; };
    auto WT = [&](int i) { return WT27 + (size_t)i * 6912; };
    auto W8 = [&](int i) { return WB8 + (size_t)i * (4 * 64 * 8); };

    pack_k<<<9, B, 0, stream>>>(w_p1, w1, w2, dw, WBp1, WT27, WB8);

    // ---- level 0 ----
    build_k<<<cgrid(N0), B, 0, stream>>>(nbr0, N0, N0, ng0, gcnt, ent);
    convp1_k<<<cgrid(N0), B, 0, stream>>>(feats, nbr0, WBp1, R0, HA, S(0), N0);
    conv16c_k<<<cgrid(N0), B, 0, stream>>>(HA, gcnt, ent, WT(0), bn1g, bn1b,
                                           S(0), i0, T, HB, S(1), N0, N0, 0);
    conv16c_k<<<cgrid(N0), B, 0, stream>>>(HB, gcnt, ent, WT(1), bn2g, bn2b,
                                           S(1), i0, R0, HA, S(2), N0, N0, 1);
    conv16_k<8><<<cgrid(N1), B, 0, stream>>>(HA, down01, W8(0), dbng, dbnb,
                                             S(2), i0, R1, HB, S(3), N1, N0, 0);

    // ---- level 1 (rebuild compact rulebook in-place; stream-serial) ----
    build_k<<<cgrid(N1), B, 0, stream>>>(nbr1, N1, N1, ng1, gcnt, ent);
    conv16c_k<<<cgrid(N1), B, 0, stream>>>(HB, gcnt, ent, WT(2), bn1g + 16, bn1b + 16,
                                           S(3), i1, T, HA, S(4), N1, N1, 0);
    conv16c_k<<<cgrid(N1), B, 0, stream>>>(HA, gcnt, ent, WT(3), bn2g + 16, bn2b + 16,
                                           S(4), i1, R1, HB, S(5), N1, N1, 1);
    conv16_k<8><<<cgrid(N2), B, 0, stream>>>(HB, down12, W8(1), dbng + 16, dbnb + 16,
                                             S(5), i1, R2, HA, S(6), N2, N1, 0);

    // ---- level 2 ----
    build_k<<<cgrid(N2), B, 0, stream>>>(nbr2, N2, N2, ng2, gcnt, ent);
    conv16c_k<<<cgrid(N2), B, 0, stream>>>(HA, gcnt, ent, WT(4), bn1g + 32, bn1b + 32,
                                           S(6), i2, T, HB, S(7), N2, N2, 0);
    conv16c_k<<<cgrid(N2), B, 0, stream>>>(HB, gcnt, ent, WT(5), bn2g + 32, bn2b + 32,
                                           S(7), i2, R2, nullptr, nullptr, N2, N2, 1);

    // ---- final concat + BN48 + ReLU + linear ----
    gstats_k<<<512, B, 0, stream>>>(R0, R1, R2, p01, p12, S(8), N0);
    fin_k<<<1, 64, 0, stream>>>(S(8), bn3g, bn3b, sb, 48, i0);
    out_k<<<lgrid(N0), B, 0, stream>>>(R0, R1, R2, p01, p12, sb, wsdf, bsdf,
                                       (float*)d_out, N0);
}